// Round 6
// baseline (611.001 us; speedup 1.0000x reference)
//
#include <hip/hip_runtime.h>
#include <hip/hip_bf16.h>
#include <hip/hip_cooperative_groups.h>

namespace cg = cooperative_groups;

#define BATCH   16384
#define NF      26
#define EDIM    32
#define DIN     832     // NF*EDIM
#define H1D     256
#define H2D     128
#define VOCAB   100000
#define BN_EPS  1e-5f

typedef float  f32x4  __attribute__((ext_vector_type(4)));
typedef __bf16 bf16x4 __attribute__((ext_vector_type(4)));
typedef __bf16 bf16x8 __attribute__((ext_vector_type(8)));

// workspace (bytes): only weights + BN stats live in HBM now
#define WS_W1T    0                  // bf16 [256][832]   425,984
#define WS_W2T    425984             // bf16 [128][256]    65,536
#define WS_S1     491520             // f32  [2][256]       2,048
#define WS_S2     493568             // f32  [2][128]       1,024

// LDS map (141,568 B total; 1 block/CU)
#define XT   0        // P1/P2: X-tile 64 x 1664B (104 slots)   [106,496 B]
                      // P3+  : Y1tile 64 x 512B @0 [32,768] ; Wt2 128 x 512B @32768 [65,536]
#define WT   106496   // P1/P2: W1 chunk 256 x 128B [32,768]    ; P5: rowacc[64] f32
#define FMO  139264   // fmL   64 f32 [256 B]
#define SCO  139520   // scL   256 f32 [1,024 B]  (P5: scL2 128)
#define SHO  140544   // shL   256 f32 [1,024 B]  (P5: shL2 128)
#define XROW 1664

__global__ __launch_bounds__(256) void k_deepfm(
    const int*   __restrict__ xc,  const float* __restrict__ lin,
    const float* __restrict__ lat, const float* __restrict__ bias,
    const float* __restrict__ W1,  const float* __restrict__ W2,
    const float* __restrict__ W3,  const float* __restrict__ b3,
    const float* __restrict__ g1,  const float* __restrict__ be1,
    const float* __restrict__ g2,  const float* __restrict__ be2,
    __bf16* __restrict__ W1T, __bf16* __restrict__ W2T,
    float* __restrict__ stats1, float* __restrict__ stats2,
    float* __restrict__ out) {
  __shared__ __align__(16) char LDS[141568];
  cg::grid_group grid = cg::this_grid();

  const int tid  = threadIdx.x;
  const int lane = tid & 63;
  const int wv   = tid >> 6;
  const int l15  = lane & 15;
  const int lq   = lane >> 4;
  const int blk  = blockIdx.x;
  const int gid  = blk * 256 + tid;

  float* fmL = (float*)(LDS + FMO);

  // ---- P0: weight convert (W1 -> bf16 W1^T, W2 -> bf16 W2^T) ----
  for (int i = gid; i < DIN * H1D; i += 65536) {
    int c = i & (H1D - 1), k = i >> 8;
    W1T[c * DIN + k] = (__bf16)W1[i];
  }
  if (gid < H1D * H2D) {
    int c = gid & (H2D - 1), k = gid >> 7;
    W2T[c * H1D + k] = (__bf16)W2[gid];
  }
  __threadfence();
  grid.sync();

  // ---- P1: stage W chunk0 + gather X-tile + FM ----
  #pragma unroll
  for (int it = 0; it < 8; ++it) {              // W1 chunk 0 -> Wt
    int lid = it * 256 + tid;
    int c = lid >> 3, s = lid & 7;
    bf16x8 w = *(const bf16x8*)(W1T + (size_t)c * DIN + s * 8);
    *(bf16x8*)(LDS + WT + c * 128 + ((s ^ (c & 7)) << 4)) = w;
  }
  {                                             // gather 1664 (row,field) pairs
    const int G = tid >> 3, e = tid & 7;
    #pragma unroll
    for (int o = 0; o < 4; ++o) {
      int idxv[13], rv[13], fv[13];
      #pragma unroll
      for (int j = 0; j < 13; ++j) {
        int p = (o * 13 + j) * 32 + G;          // 0..1663 == row*26+f
        int r = p / 26;
        rv[j] = r; fv[j] = p - r * 26;
        idxv[j] = xc[blk * (64 * NF) + p];
      }
      #pragma unroll
      for (int j = 0; j < 13; ++j) {
        f32x4 v = *(const f32x4*)(lat + ((size_t)fv[j] * VOCAB + idxv[j]) * EDIM + e * 4);
        bf16x4 b;
        #pragma unroll
        for (int q = 0; q < 4; ++q) b[q] = (__bf16)v[q];
        int slot = fv[j] * 4 + (e >> 1);
        int byte = rv[j] * XROW + ((slot ^ (rv[j] & 7)) << 4) + (e & 1) * 8;
        *(bf16x4*)(LDS + XT + byte) = b;
      }
    }
  }
  __syncthreads();
  {                                             // FM: thread = (row, dim-group)
    const int r  = tid >> 2;
    const int dg = tid & 3;
    float s8[8] = {}; float ssq = 0.f;
    #pragma unroll
    for (int f = 0; f < NF; ++f) {
      bf16x8 v = *(const bf16x8*)(LDS + XT + r * XROW + (((f * 4 + dg) ^ (r & 7)) << 4));
      #pragma unroll
      for (int q = 0; q < 8; ++q) { float x = (float)v[q]; s8[q] += x; ssq += x * x; }
    }
    float sq = 0.f;
    #pragma unroll
    for (int q = 0; q < 8; ++q) sq += s8[q] * s8[q];
    float linv = 0.f;
    #pragma unroll
    for (int f = dg; f < NF; f += 4) {
      int idx = xc[blk * (64 * NF) + r * NF + f];
      linv += lin[(size_t)f * VOCAB + idx];
    }
    float red = 0.5f * (sq - ssq) + linv;
    red += __shfl_xor(red, 1);
    red += __shfl_xor(red, 2);
    if (dg == 0) fmL[r] = red + bias[0];
  }

  // ---- P2: GEMM1 (M=64, N=256, K=832), 13 single-buffered chunks ----
  f32x4 acc[4][4] = {};
  for (int ch = 0; ch < 13; ++ch) {
    if (ch) {
      __syncthreads();
      #pragma unroll
      for (int it = 0; it < 8; ++it) {
        int lid = it * 256 + tid;
        int c = lid >> 3, s = lid & 7;
        bf16x8 w = *(const bf16x8*)(W1T + (size_t)c * DIN + ch * 64 + s * 8);
        *(bf16x8*)(LDS + WT + c * 128 + ((s ^ (c & 7)) << 4)) = w;
      }
      __syncthreads();
    }
    #pragma unroll
    for (int kk = 0; kk < 64; kk += 32) {
      bf16x8 a[4], b[4];
      #pragma unroll
      for (int mf = 0; mf < 4; ++mf) {
        int row  = mf * 16 + l15;
        int slot = ch * 8 + (kk >> 3) + lq;
        a[mf] = *(const bf16x8*)(LDS + XT + row * XROW + ((slot ^ (row & 7)) << 4));
      }
      #pragma unroll
      for (int nf = 0; nf < 4; ++nf) {
        int c    = wv * 64 + nf * 16 + l15;
        int slot = (kk >> 3) + lq;
        b[nf] = *(const bf16x8*)(LDS + WT + c * 128 + ((slot ^ (c & 7)) << 4));
      }
      #pragma unroll
      for (int mf = 0; mf < 4; ++mf)
        #pragma unroll
        for (int nf = 0; nf < 4; ++nf)
          acc[mf][nf] = __builtin_amdgcn_mfma_f32_16x16x32_bf16(a[mf], b[nf], acc[mf][nf], 0, 0, 0);
    }
  }
  // BN1 partial stats: cols are per-wave exclusive -> shfl over lq, global atomics
  #pragma unroll
  for (int nf = 0; nf < 4; ++nf) {
    float s = 0.f, q = 0.f;
    #pragma unroll
    for (int mf = 0; mf < 4; ++mf)
      #pragma unroll
      for (int r = 0; r < 4; ++r) { float v = acc[mf][nf][r]; s += v; q += v * v; }
    s += __shfl_xor(s, 16); s += __shfl_xor(s, 32);
    q += __shfl_xor(q, 16); q += __shfl_xor(q, 32);
    if (lq == 0) {
      int c = wv * 64 + nf * 16 + l15;
      atomicAdd(&stats1[c], s);
      atomicAdd(&stats1[H1D + c], q);
    }
  }
  __threadfence();
  grid.sync();

  // ---- P3: BN1 affine, acc(f32) -> relu -> bf16 Y1tile; stage Wt2 ----
  float* scL = (float*)(LDS + SCO);
  float* shL = (float*)(LDS + SHO);
  {
    float s = __hip_atomic_load(&stats1[tid],       __ATOMIC_RELAXED, __HIP_MEMORY_SCOPE_AGENT);
    float q = __hip_atomic_load(&stats1[H1D + tid], __ATOMIC_RELAXED, __HIP_MEMORY_SCOPE_AGENT);
    float m = s * (1.f / BATCH);
    float v = q * (1.f / BATCH) - m * m;
    float sc = g1[tid] * rsqrtf(v + BN_EPS);
    scL[tid] = sc;
    shL[tid] = be1[tid] - m * sc;
  }
  #pragma unroll
  for (int it = 0; it < 16; ++it) {             // W2T -> Wt2 (128 x 256 bf16)
    int lid = it * 256 + tid;
    int c = lid >> 5, ks = lid & 31;
    bf16x8 w = *(const bf16x8*)(W2T + (size_t)c * H1D + ks * 8);
    *(bf16x8*)(LDS + XT + 32768 + c * 512 + ((ks ^ (c & 7)) << 4)) = w;
  }
  __syncthreads();                              // scL ready; Xt dead (post grid sync)
  #pragma unroll
  for (int mf = 0; mf < 4; ++mf)
    #pragma unroll
    for (int nf = 0; nf < 4; ++nf) {
      int c = wv * 64 + nf * 16 + l15;
      float sc = scL[c], sh = shL[c];
      #pragma unroll
      for (int r = 0; r < 4; ++r) {
        int row = mf * 16 + lq * 4 + r;
        float h = fmaxf(acc[mf][nf][r] * sc + sh, 0.f);
        int byte = row * 512 + (((c >> 3) ^ (row & 7)) << 4) + (c & 7) * 2;
        *(__bf16*)(LDS + XT + byte) = (__bf16)h;
      }
    }
  __syncthreads();

  // ---- P4: GEMM2 (M=64, N=128, K=256), all-LDS ----
  f32x4 acc2[4][2] = {};
  #pragma unroll
  for (int kk = 0; kk < 8; ++kk) {
    bf16x8 a[4], b[2];
    #pragma unroll
    for (int mf = 0; mf < 4; ++mf) {
      int row  = mf * 16 + l15;
      int slot = kk * 4 + lq;
      a[mf] = *(const bf16x8*)(LDS + XT + row * 512 + ((slot ^ (row & 7)) << 4));
    }
    #pragma unroll
    for (int nf = 0; nf < 2; ++nf) {
      int c    = wv * 32 + nf * 16 + l15;
      int slot = kk * 4 + lq;
      b[nf] = *(const bf16x8*)(LDS + XT + 32768 + c * 512 + ((slot ^ (c & 7)) << 4));
    }
    #pragma unroll
    for (int mf = 0; mf < 4; ++mf)
      #pragma unroll
      for (int nf = 0; nf < 2; ++nf)
        acc2[mf][nf] = __builtin_amdgcn_mfma_f32_16x16x32_bf16(a[mf], b[nf], acc2[mf][nf], 0, 0, 0);
  }
  // BN2 partial stats
  #pragma unroll
  for (int nf = 0; nf < 2; ++nf) {
    float s = 0.f, q = 0.f;
    #pragma unroll
    for (int mf = 0; mf < 4; ++mf)
      #pragma unroll
      for (int r = 0; r < 4; ++r) { float v = acc2[mf][nf][r]; s += v; q += v * v; }
    s += __shfl_xor(s, 16); s += __shfl_xor(s, 32);
    q += __shfl_xor(q, 16); q += __shfl_xor(q, 32);
    if (lq == 0) {
      int c = wv * 32 + nf * 16 + l15;
      atomicAdd(&stats2[c], s);
      atomicAdd(&stats2[H2D + c], q);
    }
  }
  __threadfence();
  grid.sync();

  // ---- P5: BN2 + relu + dot(W3) + FM + bias ----
  float* rowacc = (float*)(LDS + WT);
  if (tid < H2D) {
    float s = __hip_atomic_load(&stats2[tid],       __ATOMIC_RELAXED, __HIP_MEMORY_SCOPE_AGENT);
    float q = __hip_atomic_load(&stats2[H2D + tid], __ATOMIC_RELAXED, __HIP_MEMORY_SCOPE_AGENT);
    float m = s * (1.f / BATCH);
    float v = q * (1.f / BATCH) - m * m;
    float sc = g2[tid] * rsqrtf(v + BN_EPS);
    scL[tid] = sc;
    shL[tid] = be2[tid] - m * sc;
  }
  if (tid < 64) rowacc[tid] = 0.f;
  __syncthreads();
  {
    float p[4][4] = {};                          // [mf][r]
    #pragma unroll
    for (int nf = 0; nf < 2; ++nf) {
      int c = wv * 32 + nf * 16 + l15;
      float sc = scL[c], sh = shL[c], w3 = W3[c];
      #pragma unroll
      for (int mf = 0; mf < 4; ++mf)
        #pragma unroll
        for (int r = 0; r < 4; ++r) {
          float h = fmaxf(acc2[mf][nf][r] * sc + sh, 0.f);
          p[mf][r] += h * w3;
        }
    }
    #pragma unroll
    for (int mask = 1; mask <= 8; mask <<= 1)
      #pragma unroll
      for (int mf = 0; mf < 4; ++mf)
        #pragma unroll
        for (int r = 0; r < 4; ++r) p[mf][r] += __shfl_xor(p[mf][r], mask);
    if (l15 == 0) {
      #pragma unroll
      for (int mf = 0; mf < 4; ++mf)
        #pragma unroll
        for (int r = 0; r < 4; ++r)
          atomicAdd(&rowacc[mf * 16 + lq * 4 + r], p[mf][r]);
    }
  }
  __syncthreads();
  if (tid < 64) out[blk * 64 + tid] = fmL[tid] + rowacc[tid] + b3[0];
}

// ---------------------------------------------------------------------------
extern "C" void kernel_launch(void* const* d_in, const int* in_sizes, int n_in,
                              void* d_out, int out_size, void* d_ws, size_t ws_size,
                              hipStream_t stream) {
  const int*   xc   = (const int*)  d_in[0];
  const float* lin  = (const float*)d_in[1];
  const float* lat  = (const float*)d_in[2];
  const float* W1   = (const float*)d_in[3];
  // d_in[4] = b1: cancels inside BatchNorm — unused
  const float* g1   = (const float*)d_in[5];
  const float* be1  = (const float*)d_in[6];
  const float* W2   = (const float*)d_in[7];
  // d_in[8] = b2: cancels — unused
  const float* g2   = (const float*)d_in[9];
  const float* be2  = (const float*)d_in[10];
  const float* W3   = (const float*)d_in[11];
  const float* b3   = (const float*)d_in[12];
  const float* bias = (const float*)d_in[13];

  char* ws = (char*)d_ws;
  __bf16* W1T = (__bf16*)(ws + WS_W1T);
  __bf16* W2T = (__bf16*)(ws + WS_W2T);
  float*  S1  = (float*) (ws + WS_S1);
  float*  S2  = (float*) (ws + WS_S2);
  float*  outp = (float*)d_out;

  hipMemsetAsync(S1, 0, (2 * H1D + 2 * H2D) * sizeof(float), stream);

  void* args[] = {
    (void*)&xc, (void*)&lin, (void*)&lat, (void*)&bias,
    (void*)&W1, (void*)&W2, (void*)&W3, (void*)&b3,
    (void*)&g1, (void*)&be1, (void*)&g2, (void*)&be2,
    (void*)&W1T, (void*)&W2T, (void*)&S1, (void*)&S2, (void*)&outp,
  };
  hipLaunchCooperativeKernel((void*)k_deepfm, dim3(256), dim3(256), args, 0, stream);
}